// Round 15
// baseline (1772.199 us; speedup 1.0000x reference)
//
#include <hip/hip_runtime.h>
#include <hip/hip_bf16.h>

#define BB 256
#define TT 512
#define HH 512

typedef float floatx4 __attribute__((ext_vector_type(4)));
typedef short short8 __attribute__((ext_vector_type(8)));

__device__ __forceinline__ unsigned short f2bf(float f) {
    union { float f; unsigned u; } v; v.f = f;
    unsigned r = v.u + 0x7fffu + ((v.u >> 16) & 1u);
    return (unsigned short)(r >> 16);
}
__device__ __forceinline__ float bf2f(unsigned short h) {
    union { unsigned u; float f; } v; v.u = ((unsigned)h) << 16;
    return v.f;
}
// MFMA A-fragment u16 index for (row b, col j) within a 16x512 tile (verified R3-R14).
__device__ __forceinline__ int frag16(int b, int j) {
    int kin = j & 31;
    return (j >> 5) * 512 + (b + 16 * ((kin >> 2) & 3)) * 8 + ((kin >> 4) << 2) + (kin & 3);
}

// sc0 (L1-bypass, L2-serviced) scalar load for barrier polling. BOUNDED use only;
// unbounded waits poll the R4/R7-verified agent counter.
__device__ __forceinline__ int ld_sc0(const int* p) {
    int v;
    asm volatile("global_load_dword %0, %1, off sc0\n\ts_waitcnt vmcnt(0)"
                 : "=v"(v) : "v"(p) : "memory");
    return v;
}

// ---------------- mask encoding detection ----------------
__global__ void detect_k(const unsigned char* __restrict__ s, int* __restrict__ flags)
{
    int a = 0, b = 0, c = 0;
    for (int i = blockIdx.x * blockDim.x + threadIdx.x; i < BB * TT * 2;
         i += gridDim.x * blockDim.x) {
        unsigned char v = s[i];
        if (v) {
            int m = i & 3;
            if (m == 1) a = 1;
            else if (m >= 2) b = 1;
            if ((i & 7) == 4) c = 1;
        }
    }
    if (a) atomicOr(flags, 1);
    if (b) atomicOr(flags, 2);
    if (c) atomicOr(flags, 4);
}

__global__ void canon_k(const void* __restrict__ s, const int* __restrict__ flags,
                        unsigned char* __restrict__ canon)
{
    int bt = blockIdx.x * blockDim.x + threadIdx.x;
    if (bt >= BB * TT) return;
    int f = *flags;
    int sg, sr;
    if (f & 1) {
        const unsigned char* p = (const unsigned char*)s;
        sg = p[2 * bt] != 0; sr = p[2 * bt + 1] != 0;
    } else if (f & 2) {
        const float* p = (const float*)s;
        sg = p[2 * bt] != 0.0f; sr = p[2 * bt + 1] != 0.0f;
    } else if (f & 4) {
        const int* p = (const int*)s;
        sg = p[2 * bt] != 0; sr = p[2 * bt + 1] != 0;
    } else {
        const long long* p = (const long long*)s;
        sg = p[2 * bt] != 0; sr = p[2 * bt + 1] != 0;
    }
    canon[bt] = (unsigned char)(sg | (sr << 1));
}

// ---------------- h0: encz -> hi/lo planes in frag-linear order, slot 0 ----------------
// Hp: [16 groups][4 slots][8192 u32]; per slot: hi [0,4096), lo [4096,8192).
__global__ void h0_k(const float* __restrict__ encz, unsigned* __restrict__ Hp)
{
    int i = blockIdx.x * blockDim.x + threadIdx.x;   // (b, j-pair) index
    if (i >= BB * HH / 2) return;
    int bg = i >> 8;
    int j  = (i & 255) * 2;
    float f0 = encz[bg * HH + j], f1 = encz[bg * HH + j + 1];
    unsigned short h0b = f2bf(f0), l0b = f2bf(f0 - bf2f(h0b));
    unsigned short h1b = f2bf(f1), l1b = f2bf(f1 - bf2f(h1b));
    int g = bg >> 4, b = bg & 15;
    int fi = frag16(b, j) >> 1;
    unsigned* base = Hp + (size_t)g * 32768;   // slot 0
    base[fi]        = (unsigned)h0b | ((unsigned)h1b << 16);
    base[4096 + fi] = (unsigned)l0b | ((unsigned)l1b << 16);
}

// ---------------- W1 -> bf16 hi/lo split (runs AFTER gru; aliases Hp) ----------------
__global__ void w1s_k(const float* __restrict__ W1,
                      unsigned short* __restrict__ W1h, unsigned short* __restrict__ W1l)
{
    int idx = blockIdx.x * blockDim.x + threadIdx.x;
    if (idx >= HH * HH) return;
    float f = W1[idx];
    unsigned short hb = f2bf(f);
    W1h[idx] = hb;
    W1l[idx] = f2bf(f - bf2f(hb));
}

// ---------------- persistent MFMA GRU main loop ----------------
// EXACT R14 structure (verified: gru ~1340us) with ONE change: the post-pointwise
// drain is s_waitcnt vmcnt(1) + raw s_barrier instead of __syncthreads' vmcnt(0).
// Store order is pinned (h-hi, h-lo, then decz): vmcnt retires oldest-first
// (m135-verified), so vmcnt(1) guarantees both h stores are visible at the
// coherence point while the decz store (streaming, only consumed by the next
// kernel) stays in flight off the critical path.
template <bool FAST>
__device__ __forceinline__ void gru_loop(
    unsigned* Hbase, unsigned* hstage,
    const float* dtl, const unsigned char* cnl, float* exch, const float* pwl,
    unsigned short* decz, int* gcs, int* gcf,
    const short8* Bh, const short8* Bl,
    int tid, int w, int l, int wi, int bg0)
{
    int fastspin_en = 1;

    for (int t = 0; t < TT; ++t) {
        const char* src = (const char*)(Hbase + (size_t)(t & 3) * 8192);
        unsigned*   dst = Hbase + (size_t)((t + 1) & 3) * 8192;

        // ---- stage h(t): 32 x 1KB chunks, pipelined DMA to LDS ----
        for (int c = w; c < 32; c += 6) {
            const void* gs = src + c * 1024 + l * 16;
            void* ls = (char*)hstage + c * 1024;
            __builtin_amdgcn_global_load_lds(
                (const __attribute__((address_space(1))) unsigned*)gs,
                (__attribute__((address_space(3))) unsigned*)ls, 16, 0,
                FAST ? 0x1 : 0x11);
        }
        __syncthreads();   // compiler drains vmcnt(0) -> all chunks (and old decz) done

        // ---- MFMA: direct frag reads (lane-contiguous 16B), 3 split-bf16 chains ----
        floatx4 ac0 = {0.f,0.f,0.f,0.f}, ac1 = {0.f,0.f,0.f,0.f}, ac2 = {0.f,0.f,0.f,0.f};
#pragma unroll
        for (int kt = 0; kt < 16; ++kt) {
            short8 ah = *(const short8*)((const char*)hstage + kt * 1024 + l * 16);
            short8 al = *(const short8*)((const char*)hstage + 16384 + kt * 1024 + l * 16);
            ac0 = __builtin_amdgcn_mfma_f32_16x16x32_bf16(ah, Bh[kt], ac0, 0, 0, 0);
            ac1 = __builtin_amdgcn_mfma_f32_16x16x32_bf16(ah, Bl[kt], ac1, 0, 0, 0);
            ac2 = __builtin_amdgcn_mfma_f32_16x16x32_bf16(al, Bh[kt], ac2, 0, 0, 0);
        }
        floatx4 acc = ac0 + ac1 + ac2;
        *(floatx4*)(exch + w * 256 + l * 4) = acc;
        __syncthreads();

        // ---- pointwise GRU update (threads < 256, one (b, col-pair) each) ----
        if (tid < 256) {
            const int b = tid >> 4;
            const int bgl = bg0 + b;
            const float dt = dtl[b * 516 + t];
            const unsigned char cn = cnl[b * 520 + t];
            const float sg = (cn & 1) ? 1.f : 0.f, sr = (cn & 2) ? 1.f : 0.f;
            const int jl0 = (tid * 2) & 31;
            const int j0  = wi * 32 + jl0;
            const int fi  = frag16(b, j0) >> 1;
            const unsigned hiw = hstage[fi];
            const unsigned low = hstage[4096 + fi];
            unsigned short hib[2], lob[2];
#pragma unroll
            for (int p = 0; p < 2; ++p) {
                int jl = jl0 + p;
                int lane16 = (jl & 15) + 16 * (b >> 2);
                int roff = b & 3;
                float a0 = exch[(jl >> 4) * 256 + lane16 * 4 + roff];
                float a1 = exch[(2 + (jl >> 4)) * 256 + lane16 * 4 + roff];
                float a2 = exch[(4 + (jl >> 4)) * 256 + lane16 * 4 + roff];
                float hp = bf2f((unsigned short)(p ? (hiw >> 16) : (hiw & 0xffffu))) +
                           bf2f((unsigned short)(p ? (low >> 16) : (low & 0xffffu)));
                float xr = pwl[0*32+jl]*dt + pwl[1*32+jl]*sg + pwl[2*32+jl]*sr + pwl[9*32+jl];
                float xz = pwl[3*32+jl]*dt + pwl[4*32+jl]*sg + pwl[5*32+jl]*sr + pwl[10*32+jl];
                float xn = pwl[6*32+jl]*dt + pwl[7*32+jl]*sg + pwl[8*32+jl]*sr + pwl[11*32+jl];
                float rr = 1.f / (1.f + __expf(-(xr + a0 + pwl[12*32+jl])));
                float zz = 1.f / (1.f + __expf(-(xz + a1 + pwl[13*32+jl])));
                float tx = xn + rr * (a2 + pwl[14*32+jl]);
                float ex2 = __expf(2.f * fminf(fmaxf(tx, -20.f), 20.f));
                float nn = 1.f - 2.f / (ex2 + 1.f);
                float hnew = (1.f - zz) * nn + zz * hp;
                float ho = cn ? hnew : hp;
                hib[p] = f2bf(ho);
                lob[p] = f2bf(ho - bf2f(hib[p]));
            }
            unsigned hw = (unsigned)hib[0] | ((unsigned)hib[1] << 16);
            unsigned lw = (unsigned)lob[0] | ((unsigned)lob[1] << 16);
            // PINNED ORDER: h stores first ...
            if (FAST) {
                dst[fi] = hw;              // plain store: write-through to XCD L2
                dst[4096 + fi] = lw;
            } else {
                __hip_atomic_store(dst + fi, hw, __ATOMIC_RELAXED, __HIP_MEMORY_SCOPE_AGENT);
                __hip_atomic_store(dst + 4096 + fi, lw, __ATOMIC_RELAXED, __HIP_MEMORY_SCOPE_AGENT);
            }
            __builtin_amdgcn_sched_barrier(0);
            // ... then decz (streaming; allowed to stay in flight past the barrier)
            ((unsigned*)decz)[(((size_t)bgl * TT + t) * HH + j0) >> 1] = hw;
            __builtin_amdgcn_sched_barrier(0);
        }

        // ---- group barrier ----
        if (t != TT - 1) {
            // selective drain: wait h stores (oldest 2 of 3), let decz fly
            __builtin_amdgcn_sched_barrier(0);
            asm volatile("s_waitcnt vmcnt(1)" ::: "memory");
            __builtin_amdgcn_s_barrier();
            __builtin_amdgcn_sched_barrier(0);
            int tgt = (t + 1) * 16;
            if (FAST) {
                if (tid == 64)   // wave 1: agent fallback add, off wave 0's vmcnt path
                    __hip_atomic_fetch_add(gcs, 1, __ATOMIC_RELAXED,
                                           __HIP_MEMORY_SCOPE_AGENT);
                if (tid == 0) {
                    __hip_atomic_fetch_add(gcf, 1, __ATOMIC_RELAXED,
                                           __HIP_MEMORY_SCOPE_WORKGROUP);  // L2 atomic
                    int done = 0;
                    if (fastspin_en) {
                        for (int spin = 0; spin < 256; ++spin) {
                            if (ld_sc0(gcf) >= tgt) { done = 1; break; }
                        }
                        if (!done) fastspin_en = 0;   // adaptive: sc0 poll not working
                    }
                    if (!done) {
                        while (__hip_atomic_load(gcs, __ATOMIC_RELAXED,
                                                 __HIP_MEMORY_SCOPE_AGENT) < tgt)
                            __builtin_amdgcn_s_sleep(1);
                    }
                }
            } else {
                if (tid == 0) {
                    __hip_atomic_fetch_add(gcs, 1, __ATOMIC_RELAXED,
                                           __HIP_MEMORY_SCOPE_AGENT);
                    while (__hip_atomic_load(gcs, __ATOMIC_RELAXED,
                                             __HIP_MEMORY_SCOPE_AGENT) < tgt)
                        __builtin_amdgcn_s_sleep(1);
                }
            }
            __syncthreads();
        }
    }
}

// 256 WGs x 384 threads. group g = blockIdx&15, wi = blockIdx>>4.
__global__ __launch_bounds__(384, 2) void gru_mfma(
    const float* __restrict__ dtime, const unsigned char* __restrict__ canon,
    const float* __restrict__ Wih, const float* __restrict__ Whh,
    const float* __restrict__ bih, const float* __restrict__ bhh,
    unsigned* __restrict__ Hp,             // [16][4][8192 u32]
    unsigned short* __restrict__ decz,     // [BB][TT][HH] bf16 bits
    int* __restrict__ sync)                // [0:512) agent ctr, [512:1024) L2 ctr,
                                           // [1024:1536) xcd masks, [1536:2048) det ctr
{
    __shared__ __align__(16) unsigned hstage[8192];  // 32KB
    __shared__ float dtl[16 * 516];
    __shared__ unsigned char cnl[16 * 520];
    __shared__ __align__(16) float exch[6 * 256];
    __shared__ float pwl[15 * 32];
    __shared__ int shflag;

    const int g = blockIdx.x & 15, wi = blockIdx.x >> 4;
    const int tid = threadIdx.x, w = tid >> 6, l = tid & 63;
    const int bg0 = g * 16;
    unsigned* Hbase = Hp + (size_t)g * 32768;

    for (int it = tid; it < 16 * 128; it += 384) {
        int b = it >> 7, t4 = it & 127;
        *(float4*)(dtl + b * 516 + t4 * 4) =
            *(const float4*)(dtime + (size_t)(bg0 + b) * TT + t4 * 4);
    }
    for (int it = tid; it < 16 * 128; it += 384) {
        int b = it >> 7, t4 = it & 127;
        *(unsigned*)(cnl + b * 520 + t4 * 4) =
            *(const unsigned*)(canon + (size_t)(bg0 + b) * TT + t4 * 4);
    }
    if (tid < 32) {
        int j = wi * 32 + tid;
        int r1 = HH + j, r2 = 2 * HH + j;
        pwl[0*32+tid] = Wih[j*3];   pwl[1*32+tid] = Wih[j*3+1];  pwl[2*32+tid] = Wih[j*3+2];
        pwl[3*32+tid] = Wih[r1*3];  pwl[4*32+tid] = Wih[r1*3+1]; pwl[5*32+tid] = Wih[r1*3+2];
        pwl[6*32+tid] = Wih[r2*3];  pwl[7*32+tid] = Wih[r2*3+1]; pwl[8*32+tid] = Wih[r2*3+2];
        pwl[9*32+tid]  = bih[j];  pwl[10*32+tid] = bih[r1]; pwl[11*32+tid] = bih[r2];
        pwl[12*32+tid] = bhh[j];  pwl[13*32+tid] = bhh[r1]; pwl[14*32+tid] = bhh[r2];
    }

    // ---- stationary B fragments (W_hh slice, bf16 hi+lo, 128 VGPRs) ----
    const int gate = w >> 1, ch = w & 1;
    const int rB   = gate * HH + wi * 32 + ch * 16 + (l & 15);
    const int kq4  = ((l >> 4) & 3) * 4;
    short8 Bh[16], Bl[16];
#pragma unroll
    for (int kt = 0; kt < 16; ++kt) {
        const float* wp = Whh + (size_t)rB * HH + kt * 32 + kq4;
        float4 f0 = *(const float4*)(wp);
        float4 f1 = *(const float4*)(wp + 16);
        float fs[8] = {f0.x, f0.y, f0.z, f0.w, f1.x, f1.y, f1.z, f1.w};
        short8 bh, bl;
#pragma unroll
        for (int q = 0; q < 8; ++q) {
            unsigned short hb = f2bf(fs[q]);
            bh[q] = (short)hb;
            bl[q] = (short)f2bf(fs[q] - bf2f(hb));
        }
        Bh[kt] = bh; Bl[kt] = bl;
    }

    // ---- per-group XCD-purity detection (R10-verified, 16 co-resident WGs) ----
    unsigned xcc;
    asm volatile("s_getreg_b32 %0, hwreg(HW_REG_XCC_ID)" : "=s"(xcc));
    if (tid == 0) {
        __hip_atomic_fetch_or((unsigned*)&sync[1024 + g * 32], 1u << (xcc & 31),
                              __ATOMIC_RELAXED, __HIP_MEMORY_SCOPE_AGENT);
        asm volatile("s_waitcnt vmcnt(0)" ::: "memory");   // OR committed before arrival
        __hip_atomic_fetch_add(&sync[1536 + g * 32], 1, __ATOMIC_RELAXED,
                               __HIP_MEMORY_SCOPE_AGENT);
        while (__hip_atomic_load(&sync[1536 + g * 32], __ATOMIC_RELAXED,
                                 __HIP_MEMORY_SCOPE_AGENT) < 16)
            __builtin_amdgcn_s_sleep(2);
        unsigned m = __hip_atomic_load((unsigned*)&sync[1024 + g * 32], __ATOMIC_RELAXED,
                                       __HIP_MEMORY_SCOPE_AGENT);
        shflag = (__popc(m) == 1) ? 1 : 0;
    }
    __syncthreads();
    const int fast = shflag;

    int* gcs = sync + g * 32;
    int* gcf = sync + 512 + g * 32;
    if (fast)
        gru_loop<true>(Hbase, hstage, dtl, cnl, exch, pwl, decz, gcs, gcf, Bh, Bl,
                       tid, w, l, wi, bg0);
    else
        gru_loop<false>(Hbase, hstage, dtl, cnl, exch, pwl, decz, gcs, gcf, Bh, Bl,
                        tid, w, l, wi, bg0);
}

// ---------------- FF head: decx = W2 . relu(decz @ W1^T + b1) + b2 ----------------
__global__ __launch_bounds__(512) void ff_mfma(
    const unsigned short* __restrict__ decz,
    const unsigned short* __restrict__ W1h, const unsigned short* __restrict__ W1l,
    const float* __restrict__ b1, const float* __restrict__ W2,
    const float* __restrict__ b2, float* __restrict__ decx)
{
    __shared__ __align__(16) unsigned short wst[2 * 512 * 32];  // 64KB

    const int wv = threadIdx.x >> 6, l = threadIdx.x & 63;
    const int row0 = blockIdx.x * 128 + wv * 16;
    const int mrow = l & 15, q = l >> 4;
    const unsigned short* arow = decz + (size_t)(row0 + mrow) * HH;

    floatx4 acc[32];
#pragma unroll
    for (int f = 0; f < 32; ++f) acc[f] = (floatx4){0.f, 0.f, 0.f, 0.f};

    for (int kt = 0; kt < 16; ++kt) {
        __syncthreads();
        for (int it = threadIdx.x; it < 8192; it += 512) {
            int plane = it >> 12, rest = it & 4095;
            int n = rest >> 3, q4 = rest & 7;
            const unsigned short* gp =
                (plane ? W1l : W1h) + (size_t)n * HH + kt * 32 + q4 * 4;
            uint2 v = *(const uint2*)gp;
            int e0 = (q4 & 3) * 8 + (q4 >> 2) * 4;
            *(uint2*)(wst + plane * 16384 + n * 32 + e0) = v;
        }
        __syncthreads();

        const int k0 = kt * 32 + q * 4;
        union { unsigned u[4]; short8 s; } a;
        *(uint2*)&a.u[0] = *(const uint2*)(arow + k0);
        *(uint2*)&a.u[2] = *(const uint2*)(arow + k0 + 16);
#pragma unroll
        for (int f = 0; f < 32; ++f) {
            const int n = f * 16 + mrow;
            short8 bh = *(const short8*)(wst + n * 32 + q * 8);
            short8 bl = *(const short8*)(wst + 16384 + n * 32 + q * 8);
            acc[f] = __builtin_amdgcn_mfma_f32_16x16x32_bf16(a.s, bh, acc[f], 0, 0, 0);
            acc[f] = __builtin_amdgcn_mfma_f32_16x16x32_bf16(a.s, bl, acc[f], 0, 0, 0);
        }
    }

    float res[4] = {0.f, 0.f, 0.f, 0.f};
#pragma unroll
    for (int f = 0; f < 32; ++f) {
        int n = f * 16 + mrow;
        float w2v = W2[n], b1v = b1[n];
#pragma unroll
        for (int i = 0; i < 4; ++i)
            res[i] += w2v * fmaxf(acc[f][i] + b1v, 0.f);
    }
    const float b2v = b2[0];
#pragma unroll
    for (int i = 0; i < 4; ++i) {
        float v = res[i];
        v += __shfl_xor(v, 1, 64);
        v += __shfl_xor(v, 2, 64);
        v += __shfl_xor(v, 4, 64);
        v += __shfl_xor(v, 8, 64);
        if (mrow == 0) decx[row0 + q * 4 + i] = v + b2v;
    }
}

// ---------------- serial -> parallel scatter (wave-parallel ballot prefix) ----------------
__global__ void scatter_k(const unsigned char* __restrict__ canon,
                          const float* __restrict__ decx, float* __restrict__ out)
{
    int wid = (blockIdx.x * blockDim.x + threadIdx.x) >> 6;
    int lane = threadIdx.x & 63;
    if (wid >= 2 * BB) return;
    int kb = wid >> 8, b = wid & 255;
    int cnt = 0;
    for (int t0 = 0; t0 < TT; t0 += 64) {
        unsigned char c = canon[b * TT + t0 + lane];
        int pred = (c >> kb) & 1;
        unsigned long long m = __ballot(pred);
        if (pred) {
            int pos = cnt + __popcll(m & ((1ull << lane) - 1ull));
            out[((size_t)kb * BB + b) * TT + pos] = decx[b * TT + t0 + lane];
        }
        cnt += __popcll(m);
    }
}

extern "C" void kernel_launch(void* const* d_in, const int* in_sizes, int n_in,
                              void* d_out, int out_size, void* d_ws, size_t ws_size,
                              hipStream_t stream)
{
    const float* dtime    = (const float*)d_in[0];
    const void*  s_onehot = d_in[1];
    // d_in[2] (onehot/valid) never read: valid == s_g | s_r by construction.
    const float* encz = (const float*)d_in[3];
    const float* Wih  = (const float*)d_in[4];
    const float* Whh  = (const float*)d_in[5];
    const float* bih  = (const float*)d_in[6];
    const float* bhh  = (const float*)d_in[7];
    const float* W1   = (const float*)d_in[8];
    const float* b1   = (const float*)d_in[9];
    const float* W2   = (const float*)d_in[10];
    const float* b2   = (const float*)d_in[11];

    char* ws = (char*)d_ws;
    int*            sync  = (int*)ws;                        // 8KB
    int*            flags = (int*)(ws + 8192);               // 256B
    unsigned char*  canon = (unsigned char*)(ws + 8704);     // 128KB
    unsigned*       Hp    = (unsigned*)(ws + 8704 + BB * TT);              // 2MB
    unsigned short* decz  = (unsigned short*)((char*)Hp + 16 * 32768 * 4); // 128MB
    // Post-GRU region aliases Hp (dead after gru): W1h 512KB, W1l 512KB, decx 512KB.
    unsigned short* W1h   = (unsigned short*)Hp;
    unsigned short* W1l   = W1h + HH * HH;
    float*          decx  = (float*)(W1l + HH * HH);

    hipMemsetAsync(ws, 0, 8448, stream);   // sync counters + flags
    detect_k<<<32, 256, 0, stream>>>((const unsigned char*)s_onehot, flags);
    canon_k<<<(BB * TT + 255) / 256, 256, 0, stream>>>(s_onehot, flags, canon);
    h0_k<<<(BB * HH / 2 + 255) / 256, 256, 0, stream>>>(encz, Hp);

    gru_mfma<<<256, 384, 0, stream>>>(dtime, canon, Wih, Whh, bih, bhh,
                                      Hp, decz, sync);

    w1s_k<<<(HH * HH + 255) / 256, 256, 0, stream>>>(W1, W1h, W1l);
    ff_mfma<<<BB * TT / 128, 512, 0, stream>>>(decz, W1h, W1l, b1, W2, b2, decx);

    hipMemsetAsync(d_out, 0, (size_t)out_size * sizeof(float), stream);
    scatter_k<<<128, 256, 0, stream>>>(canon, decx, (float*)d_out);
}

// Round 16
// 1457.213 us; speedup vs baseline: 1.2162x; 1.2162x over previous
//
#include <hip/hip_runtime.h>
#include <hip/hip_bf16.h>

#define BB 256
#define TT 512
#define HH 512

typedef float floatx4 __attribute__((ext_vector_type(4)));
typedef short short8 __attribute__((ext_vector_type(8)));

__device__ __forceinline__ unsigned short f2bf(float f) {
    union { float f; unsigned u; } v; v.f = f;
    unsigned r = v.u + 0x7fffu + ((v.u >> 16) & 1u);
    return (unsigned short)(r >> 16);
}
__device__ __forceinline__ float bf2f(unsigned short h) {
    union { unsigned u; float f; } v; v.u = ((unsigned)h) << 16;
    return v.f;
}
// MFMA A-fragment u16 index for (row b, col j) within a 16x512 tile (verified R3-R15).
__device__ __forceinline__ int frag16(int b, int j) {
    int kin = j & 31;
    return (j >> 5) * 512 + (b + 16 * ((kin >> 2) & 3)) * 8 + ((kin >> 4) << 2) + (kin & 3);
}

// sc0 (L1-bypass, L2-serviced) scalar load for barrier polling. BOUNDED use only;
// unbounded waits poll the R4/R7-verified agent counter.
__device__ __forceinline__ int ld_sc0(const int* p) {
    int v;
    asm volatile("global_load_dword %0, %1, off sc0\n\ts_waitcnt vmcnt(0)"
                 : "=v"(v) : "v"(p) : "memory");
    return v;
}

// ---------------- mask encoding detection ----------------
__global__ void detect_k(const unsigned char* __restrict__ s, int* __restrict__ flags)
{
    int a = 0, b = 0, c = 0;
    for (int i = blockIdx.x * blockDim.x + threadIdx.x; i < BB * TT * 2;
         i += gridDim.x * blockDim.x) {
        unsigned char v = s[i];
        if (v) {
            int m = i & 3;
            if (m == 1) a = 1;
            else if (m >= 2) b = 1;
            if ((i & 7) == 4) c = 1;
        }
    }
    if (a) atomicOr(flags, 1);
    if (b) atomicOr(flags, 2);
    if (c) atomicOr(flags, 4);
}

__global__ void canon_k(const void* __restrict__ s, const int* __restrict__ flags,
                        unsigned char* __restrict__ canon)
{
    int bt = blockIdx.x * blockDim.x + threadIdx.x;
    if (bt >= BB * TT) return;
    int f = *flags;
    int sg, sr;
    if (f & 1) {
        const unsigned char* p = (const unsigned char*)s;
        sg = p[2 * bt] != 0; sr = p[2 * bt + 1] != 0;
    } else if (f & 2) {
        const float* p = (const float*)s;
        sg = p[2 * bt] != 0.0f; sr = p[2 * bt + 1] != 0.0f;
    } else if (f & 4) {
        const int* p = (const int*)s;
        sg = p[2 * bt] != 0; sr = p[2 * bt + 1] != 0;
    } else {
        const long long* p = (const long long*)s;
        sg = p[2 * bt] != 0; sr = p[2 * bt + 1] != 0;
    }
    canon[bt] = (unsigned char)(sg | (sr << 1));
}

// ---------------- h0: encz -> hi/lo planes in frag-linear order, slot 0 ----------------
// Hp: [16 groups][4 slots][8192 u32]; per slot: hi [0,4096), lo [4096,8192).
__global__ void h0_k(const float* __restrict__ encz, unsigned* __restrict__ Hp)
{
    int i = blockIdx.x * blockDim.x + threadIdx.x;   // (b, j-pair) index
    if (i >= BB * HH / 2) return;
    int bg = i >> 8;
    int j  = (i & 255) * 2;
    float f0 = encz[bg * HH + j], f1 = encz[bg * HH + j + 1];
    unsigned short h0b = f2bf(f0), l0b = f2bf(f0 - bf2f(h0b));
    unsigned short h1b = f2bf(f1), l1b = f2bf(f1 - bf2f(h1b));
    int g = bg >> 4, b = bg & 15;
    int fi = frag16(b, j) >> 1;
    unsigned* base = Hp + (size_t)g * 32768;   // slot 0
    base[fi]        = (unsigned)h0b | ((unsigned)h1b << 16);
    base[4096 + fi] = (unsigned)l0b | ((unsigned)l1b << 16);
}

// ---------------- W1 -> bf16 hi plane (runs AFTER gru; aliases Hp) ----------------
__global__ void w1h_k(const float* __restrict__ W1, unsigned short* __restrict__ W1h)
{
    int idx = blockIdx.x * blockDim.x + threadIdx.x;
    if (idx >= HH * HH) return;
    W1h[idx] = f2bf(W1[idx]);
}

// ---------------- persistent MFMA GRU main loop (EXACT R14, verified ~1340us) ----------------
template <bool FAST>
__device__ __forceinline__ void gru_loop(
    unsigned* Hbase, unsigned* hstage,
    const float* dtl, const unsigned char* cnl, float* exch, const float* pwl,
    unsigned short* decz, int* gcs, int* gcf,
    const short8* Bh, const short8* Bl,
    int tid, int w, int l, int wi, int bg0)
{
    int fastspin_en = 1;

    for (int t = 0; t < TT; ++t) {
        const char* src = (const char*)(Hbase + (size_t)(t & 3) * 8192);
        unsigned*   dst = Hbase + (size_t)((t + 1) & 3) * 8192;

        // ---- stage h(t): 32 x 1KB chunks, pipelined DMA to LDS ----
        for (int c = w; c < 32; c += 6) {
            const void* gs = src + c * 1024 + l * 16;
            void* ls = (char*)hstage + c * 1024;
            __builtin_amdgcn_global_load_lds(
                (const __attribute__((address_space(1))) unsigned*)gs,
                (__attribute__((address_space(3))) unsigned*)ls, 16, 0,
                FAST ? 0x1 : 0x11);
        }
        __syncthreads();   // compiler drains vmcnt(0) -> all chunks in LDS

        // ---- MFMA: direct frag reads (lane-contiguous 16B), 3 split-bf16 chains ----
        floatx4 ac0 = {0.f,0.f,0.f,0.f}, ac1 = {0.f,0.f,0.f,0.f}, ac2 = {0.f,0.f,0.f,0.f};
#pragma unroll
        for (int kt = 0; kt < 16; ++kt) {
            short8 ah = *(const short8*)((const char*)hstage + kt * 1024 + l * 16);
            short8 al = *(const short8*)((const char*)hstage + 16384 + kt * 1024 + l * 16);
            ac0 = __builtin_amdgcn_mfma_f32_16x16x32_bf16(ah, Bh[kt], ac0, 0, 0, 0);
            ac1 = __builtin_amdgcn_mfma_f32_16x16x32_bf16(ah, Bl[kt], ac1, 0, 0, 0);
            ac2 = __builtin_amdgcn_mfma_f32_16x16x32_bf16(al, Bh[kt], ac2, 0, 0, 0);
        }
        floatx4 acc = ac0 + ac1 + ac2;
        *(floatx4*)(exch + w * 256 + l * 4) = acc;
        __syncthreads();

        // ---- pointwise GRU update (threads < 256, one (b, col-pair) each) ----
        if (tid < 256) {
            const int b = tid >> 4;
            const int bgl = bg0 + b;
            const float dt = dtl[b * 516 + t];
            const unsigned char cn = cnl[b * 520 + t];
            const float sg = (cn & 1) ? 1.f : 0.f, sr = (cn & 2) ? 1.f : 0.f;
            const int jl0 = (tid * 2) & 31;
            const int j0  = wi * 32 + jl0;
            const int fi  = frag16(b, j0) >> 1;
            const unsigned hiw = hstage[fi];
            const unsigned low = hstage[4096 + fi];
            unsigned short hib[2], lob[2];
#pragma unroll
            for (int p = 0; p < 2; ++p) {
                int jl = jl0 + p;
                int lane16 = (jl & 15) + 16 * (b >> 2);
                int roff = b & 3;
                float a0 = exch[(jl >> 4) * 256 + lane16 * 4 + roff];
                float a1 = exch[(2 + (jl >> 4)) * 256 + lane16 * 4 + roff];
                float a2 = exch[(4 + (jl >> 4)) * 256 + lane16 * 4 + roff];
                float hp = bf2f((unsigned short)(p ? (hiw >> 16) : (hiw & 0xffffu))) +
                           bf2f((unsigned short)(p ? (low >> 16) : (low & 0xffffu)));
                float xr = pwl[0*32+jl]*dt + pwl[1*32+jl]*sg + pwl[2*32+jl]*sr + pwl[9*32+jl];
                float xz = pwl[3*32+jl]*dt + pwl[4*32+jl]*sg + pwl[5*32+jl]*sr + pwl[10*32+jl];
                float xn = pwl[6*32+jl]*dt + pwl[7*32+jl]*sg + pwl[8*32+jl]*sr + pwl[11*32+jl];
                float rr = 1.f / (1.f + __expf(-(xr + a0 + pwl[12*32+jl])));
                float zz = 1.f / (1.f + __expf(-(xz + a1 + pwl[13*32+jl])));
                float tx = xn + rr * (a2 + pwl[14*32+jl]);
                float ex2 = __expf(2.f * fminf(fmaxf(tx, -20.f), 20.f));
                float nn = 1.f - 2.f / (ex2 + 1.f);
                float hnew = (1.f - zz) * nn + zz * hp;
                float ho = cn ? hnew : hp;
                hib[p] = f2bf(ho);
                lob[p] = f2bf(ho - bf2f(hib[p]));
            }
            unsigned hw = (unsigned)hib[0] | ((unsigned)hib[1] << 16);
            unsigned lw = (unsigned)lob[0] | ((unsigned)lob[1] << 16);
            if (FAST) {
                dst[fi] = hw;              // plain store: write-through to XCD L2
                dst[4096 + fi] = lw;
            } else {
                __hip_atomic_store(dst + fi, hw, __ATOMIC_RELAXED, __HIP_MEMORY_SCOPE_AGENT);
                __hip_atomic_store(dst + 4096 + fi, lw, __ATOMIC_RELAXED, __HIP_MEMORY_SCOPE_AGENT);
            }
            ((unsigned*)decz)[(((size_t)bgl * TT + t) * HH + j0) >> 1] = hw;
        }

        // ---- group barrier ----
        if (t != TT - 1) {
            __syncthreads();   // vmcnt(0) drain -> h stores complete at coherence point
            int tgt = (t + 1) * 16;
            if (FAST) {
                if (tid == 64)   // wave 1: agent fallback add, off wave 0's vmcnt path
                    __hip_atomic_fetch_add(gcs, 1, __ATOMIC_RELAXED,
                                           __HIP_MEMORY_SCOPE_AGENT);
                if (tid == 0) {
                    __hip_atomic_fetch_add(gcf, 1, __ATOMIC_RELAXED,
                                           __HIP_MEMORY_SCOPE_WORKGROUP);  // L2 atomic
                    int done = 0;
                    if (fastspin_en) {
                        for (int spin = 0; spin < 256; ++spin) {
                            if (ld_sc0(gcf) >= tgt) { done = 1; break; }
                        }
                        if (!done) fastspin_en = 0;   // adaptive: sc0 poll not working
                    }
                    if (!done) {
                        while (__hip_atomic_load(gcs, __ATOMIC_RELAXED,
                                                 __HIP_MEMORY_SCOPE_AGENT) < tgt)
                            __builtin_amdgcn_s_sleep(1);
                    }
                }
            } else {
                if (tid == 0) {
                    __hip_atomic_fetch_add(gcs, 1, __ATOMIC_RELAXED,
                                           __HIP_MEMORY_SCOPE_AGENT);
                    while (__hip_atomic_load(gcs, __ATOMIC_RELAXED,
                                             __HIP_MEMORY_SCOPE_AGENT) < tgt)
                        __builtin_amdgcn_s_sleep(1);
                }
            }
            __syncthreads();
        }
    }
}

// 256 WGs x 384 threads. group g = blockIdx&15, wi = blockIdx>>4.
__global__ __launch_bounds__(384, 2) void gru_mfma(
    const float* __restrict__ dtime, const unsigned char* __restrict__ canon,
    const float* __restrict__ Wih, const float* __restrict__ Whh,
    const float* __restrict__ bih, const float* __restrict__ bhh,
    unsigned* __restrict__ Hp,             // [16][4][8192 u32]
    unsigned short* __restrict__ decz,     // [BB][TT][HH] bf16 bits
    int* __restrict__ sync)
{
    __shared__ __align__(16) unsigned hstage[8192];  // 32KB
    __shared__ float dtl[16 * 516];
    __shared__ unsigned char cnl[16 * 520];
    __shared__ __align__(16) float exch[6 * 256];
    __shared__ float pwl[15 * 32];
    __shared__ int shflag;

    const int g = blockIdx.x & 15, wi = blockIdx.x >> 4;
    const int tid = threadIdx.x, w = tid >> 6, l = tid & 63;
    const int bg0 = g * 16;
    unsigned* Hbase = Hp + (size_t)g * 32768;

    for (int it = tid; it < 16 * 128; it += 384) {
        int b = it >> 7, t4 = it & 127;
        *(float4*)(dtl + b * 516 + t4 * 4) =
            *(const float4*)(dtime + (size_t)(bg0 + b) * TT + t4 * 4);
    }
    for (int it = tid; it < 16 * 128; it += 384) {
        int b = it >> 7, t4 = it & 127;
        *(unsigned*)(cnl + b * 520 + t4 * 4) =
            *(const unsigned*)(canon + (size_t)(bg0 + b) * TT + t4 * 4);
    }
    if (tid < 32) {
        int j = wi * 32 + tid;
        int r1 = HH + j, r2 = 2 * HH + j;
        pwl[0*32+tid] = Wih[j*3];   pwl[1*32+tid] = Wih[j*3+1];  pwl[2*32+tid] = Wih[j*3+2];
        pwl[3*32+tid] = Wih[r1*3];  pwl[4*32+tid] = Wih[r1*3+1]; pwl[5*32+tid] = Wih[r1*3+2];
        pwl[6*32+tid] = Wih[r2*3];  pwl[7*32+tid] = Wih[r2*3+1]; pwl[8*32+tid] = Wih[r2*3+2];
        pwl[9*32+tid]  = bih[j];  pwl[10*32+tid] = bih[r1]; pwl[11*32+tid] = bih[r2];
        pwl[12*32+tid] = bhh[j];  pwl[13*32+tid] = bhh[r1]; pwl[14*32+tid] = bhh[r2];
    }

    // ---- stationary B fragments (W_hh slice, bf16 hi+lo, 128 VGPRs) ----
    const int gate = w >> 1, ch = w & 1;
    const int rB   = gate * HH + wi * 32 + ch * 16 + (l & 15);
    const int kq4  = ((l >> 4) & 3) * 4;
    short8 Bh[16], Bl[16];
#pragma unroll
    for (int kt = 0; kt < 16; ++kt) {
        const float* wp = Whh + (size_t)rB * HH + kt * 32 + kq4;
        float4 f0 = *(const float4*)(wp);
        float4 f1 = *(const float4*)(wp + 16);
        float fs[8] = {f0.x, f0.y, f0.z, f0.w, f1.x, f1.y, f1.z, f1.w};
        short8 bh, bl;
#pragma unroll
        for (int q = 0; q < 8; ++q) {
            unsigned short hb = f2bf(fs[q]);
            bh[q] = (short)hb;
            bl[q] = (short)f2bf(fs[q] - bf2f(hb));
        }
        Bh[kt] = bh; Bl[kt] = bl;
    }

    // ---- per-group XCD-purity detection (R10-verified, 16 co-resident WGs) ----
    unsigned xcc;
    asm volatile("s_getreg_b32 %0, hwreg(HW_REG_XCC_ID)" : "=s"(xcc));
    if (tid == 0) {
        __hip_atomic_fetch_or((unsigned*)&sync[1024 + g * 32], 1u << (xcc & 31),
                              __ATOMIC_RELAXED, __HIP_MEMORY_SCOPE_AGENT);
        asm volatile("s_waitcnt vmcnt(0)" ::: "memory");   // OR committed before arrival
        __hip_atomic_fetch_add(&sync[1536 + g * 32], 1, __ATOMIC_RELAXED,
                               __HIP_MEMORY_SCOPE_AGENT);
        while (__hip_atomic_load(&sync[1536 + g * 32], __ATOMIC_RELAXED,
                                 __HIP_MEMORY_SCOPE_AGENT) < 16)
            __builtin_amdgcn_s_sleep(2);
        unsigned m = __hip_atomic_load((unsigned*)&sync[1024 + g * 32], __ATOMIC_RELAXED,
                                       __HIP_MEMORY_SCOPE_AGENT);
        shflag = (__popc(m) == 1) ? 1 : 0;
    }
    __syncthreads();
    const int fast = shflag;

    int* gcs = sync + g * 32;
    int* gcf = sync + 512 + g * 32;
    if (fast)
        gru_loop<true>(Hbase, hstage, dtl, cnl, exch, pwl, decz, gcs, gcf, Bh, Bl,
                       tid, w, l, wi, bg0);
    else
        gru_loop<false>(Hbase, hstage, dtl, cnl, exch, pwl, decz, gcs, gcf, Bh, Bl,
                        tid, w, l, wi, bg0);
}

// ---------------- FF head: decx = W2 . relu(decz @ W1^T + b1) + b2 ----------------
// W1 hi-plane only (bf16): halves MFMA count, W1 traffic, and LDS staging vs R15.
// Error budget: +2-4e-3 absmax on top of 3.9e-3, threshold 2.02e-2.
__global__ __launch_bounds__(512) void ff_mfma(
    const unsigned short* __restrict__ decz,
    const unsigned short* __restrict__ W1h,
    const float* __restrict__ b1, const float* __restrict__ W2,
    const float* __restrict__ b2, float* __restrict__ decx)
{
    __shared__ __align__(16) unsigned short wst[512 * 32];  // 32KB

    const int wv = threadIdx.x >> 6, l = threadIdx.x & 63;
    const int row0 = blockIdx.x * 128 + wv * 16;
    const int mrow = l & 15, q = l >> 4;
    const unsigned short* arow = decz + (size_t)(row0 + mrow) * HH;

    floatx4 acc[32];
#pragma unroll
    for (int f = 0; f < 32; ++f) acc[f] = (floatx4){0.f, 0.f, 0.f, 0.f};

    for (int kt = 0; kt < 16; ++kt) {
        __syncthreads();
        // stage W1 hi chunk [512 n][32 k'] in frag-e8 order
        for (int it = threadIdx.x; it < 4096; it += 512) {
            int n = it >> 3, q4 = it & 7;
            const unsigned short* gp = W1h + (size_t)n * HH + kt * 32 + q4 * 4;
            uint2 v = *(const uint2*)gp;
            int e0 = (q4 & 3) * 8 + (q4 >> 2) * 4;
            *(uint2*)(wst + n * 32 + e0) = v;
        }
        __syncthreads();

        const int k0 = kt * 32 + q * 4;
        union { unsigned u[4]; short8 s; } a;
        *(uint2*)&a.u[0] = *(const uint2*)(arow + k0);
        *(uint2*)&a.u[2] = *(const uint2*)(arow + k0 + 16);
#pragma unroll
        for (int f = 0; f < 32; ++f) {
            const int n = f * 16 + mrow;
            short8 bh = *(const short8*)(wst + n * 32 + q * 8);
            acc[f] = __builtin_amdgcn_mfma_f32_16x16x32_bf16(a.s, bh, acc[f], 0, 0, 0);
        }
    }

    float res[4] = {0.f, 0.f, 0.f, 0.f};
#pragma unroll
    for (int f = 0; f < 32; ++f) {
        int n = f * 16 + mrow;
        float w2v = W2[n], b1v = b1[n];
#pragma unroll
        for (int i = 0; i < 4; ++i)
            res[i] += w2v * fmaxf(acc[f][i] + b1v, 0.f);
    }
    const float b2v = b2[0];
#pragma unroll
    for (int i = 0; i < 4; ++i) {
        float v = res[i];
        v += __shfl_xor(v, 1, 64);
        v += __shfl_xor(v, 2, 64);
        v += __shfl_xor(v, 4, 64);
        v += __shfl_xor(v, 8, 64);
        if (mrow == 0) decx[row0 + q * 4 + i] = v + b2v;
    }
}

// ---------------- serial -> parallel scatter (wave-parallel ballot prefix) ----------------
__global__ void scatter_k(const unsigned char* __restrict__ canon,
                          const float* __restrict__ decx, float* __restrict__ out)
{
    int wid = (blockIdx.x * blockDim.x + threadIdx.x) >> 6;
    int lane = threadIdx.x & 63;
    if (wid >= 2 * BB) return;
    int kb = wid >> 8, b = wid & 255;
    int cnt = 0;
    for (int t0 = 0; t0 < TT; t0 += 64) {
        unsigned char c = canon[b * TT + t0 + lane];
        int pred = (c >> kb) & 1;
        unsigned long long m = __ballot(pred);
        if (pred) {
            int pos = cnt + __popcll(m & ((1ull << lane) - 1ull));
            out[((size_t)kb * BB + b) * TT + pos] = decx[b * TT + t0 + lane];
        }
        cnt += __popcll(m);
    }
}

extern "C" void kernel_launch(void* const* d_in, const int* in_sizes, int n_in,
                              void* d_out, int out_size, void* d_ws, size_t ws_size,
                              hipStream_t stream)
{
    const float* dtime    = (const float*)d_in[0];
    const void*  s_onehot = d_in[1];
    // d_in[2] (onehot/valid) never read: valid == s_g | s_r by construction.
    const float* encz = (const float*)d_in[3];
    const float* Wih  = (const float*)d_in[4];
    const float* Whh  = (const float*)d_in[5];
    const float* bih  = (const float*)d_in[6];
    const float* bhh  = (const float*)d_in[7];
    const float* W1   = (const float*)d_in[8];
    const float* b1   = (const float*)d_in[9];
    const float* W2   = (const float*)d_in[10];
    const float* b2   = (const float*)d_in[11];

    char* ws = (char*)d_ws;
    int*            sync  = (int*)ws;                        // 8KB
    int*            flags = (int*)(ws + 8192);               // 256B
    unsigned char*  canon = (unsigned char*)(ws + 8704);     // 128KB
    unsigned*       Hp    = (unsigned*)(ws + 8704 + BB * TT);              // 2MB
    unsigned short* decz  = (unsigned short*)((char*)Hp + 16 * 32768 * 4); // 128MB
    // Post-GRU region aliases Hp (dead after gru): W1h 512KB, decx 512KB.
    unsigned short* W1h   = (unsigned short*)Hp;
    float*          decx  = (float*)(W1h + HH * HH);

    hipMemsetAsync(ws, 0, 8448, stream);   // sync counters + flags
    detect_k<<<32, 256, 0, stream>>>((const unsigned char*)s_onehot, flags);
    canon_k<<<(BB * TT + 255) / 256, 256, 0, stream>>>(s_onehot, flags, canon);
    h0_k<<<(BB * HH / 2 + 255) / 256, 256, 0, stream>>>(encz, Hp);

    gru_mfma<<<256, 384, 0, stream>>>(dtime, canon, Wih, Whh, bih, bhh,
                                      Hp, decz, sync);

    w1h_k<<<(HH * HH + 255) / 256, 256, 0, stream>>>(W1, W1h);
    ff_mfma<<<BB * TT / 128, 512, 0, stream>>>(decz, W1h, b1, W2, b2, decx);

    hipMemsetAsync(d_out, 0, (size_t)out_size * sizeof(float), stream);
    scatter_k<<<128, 256, 0, stream>>>(canon, decx, (float*)d_out);
}